// Round 3
// baseline (494.924 us; speedup 1.0000x reference)
//
#include <hip/hip_runtime.h>
#include <hip/hip_bf16.h>

#define NN 8192
#define FF 128

typedef unsigned short ushort_t;
typedef __attribute__((ext_vector_type(4))) float f32x4;
typedef __attribute__((ext_vector_type(4))) int i32x4;
typedef __attribute__((ext_vector_type(8))) short s16x8;

// ---------------- Kernel 1: h = X @ W  -> hT (bf16, [128][8192]), s1, U=exp(s2), V=exp(.01 s2)
__global__ __launch_bounds__(256)
void k1_hw(const float* __restrict__ inp, const float* __restrict__ W,
           const float* __restrict__ a, ushort_t* __restrict__ hT,
           float* __restrict__ s1g, float* __restrict__ Ug, float* __restrict__ Vg)
{
  __shared__ float Wl[FF * FF];     // 64 KB
  __shared__ float il[32 * 129];    // padded, ~16 KB
  __shared__ float red1[32 * 8];
  __shared__ float red2[32 * 8];
  const int t = threadIdx.x;
  const int ib = blockIdx.x * 32;

  {
    const float4* Ws = (const float4*)W;
    float4* Wd = (float4*)Wl;
#pragma unroll
    for (int q = 0; q < 16; ++q) Wd[t + 256 * q] = Ws[t + 256 * q];
  }
#pragma unroll
  for (int q = 0; q < 4; ++q) {
    int idx = t + 256 * q;
    int r = idx >> 5, c4 = idx & 31;
    float4 v = ((const float4*)(inp + (size_t)(ib + r) * FF))[c4];
    float* dst = &il[r * 129 + c4 * 4];
    dst[0] = v.x; dst[1] = v.y; dst[2] = v.z; dst[3] = v.w;
  }
  __syncthreads();

  const int r = t & 31;
  const int c0 = (t >> 5) * 16;
  float acc[16];
#pragma unroll
  for (int j = 0; j < 16; ++j) acc[j] = 0.f;

#pragma unroll 4
  for (int k = 0; k < FF; ++k) {
    float iv = il[r * 129 + k];
    const float4* wrow = (const float4*)&Wl[k * FF + c0];
    float4 w0 = wrow[0], w1 = wrow[1], w2 = wrow[2], w3 = wrow[3];
    acc[0]  += iv * w0.x; acc[1]  += iv * w0.y; acc[2]  += iv * w0.z; acc[3]  += iv * w0.w;
    acc[4]  += iv * w1.x; acc[5]  += iv * w1.y; acc[6]  += iv * w1.z; acc[7]  += iv * w1.w;
    acc[8]  += iv * w2.x; acc[9]  += iv * w2.y; acc[10] += iv * w2.z; acc[11] += iv * w2.w;
    acc[12] += iv * w3.x; acc[13] += iv * w3.y; acc[14] += iv * w3.z; acc[15] += iv * w3.w;
  }

  float ps1 = 0.f, ps2 = 0.f;
#pragma unroll
  for (int q = 0; q < 4; ++q) {
    float4 a1v = *(const float4*)(a + c0 + 4 * q);
    float4 a2v = *(const float4*)(a + FF + c0 + 4 * q);
    ps1 += acc[4*q+0]*a1v.x + acc[4*q+1]*a1v.y + acc[4*q+2]*a1v.z + acc[4*q+3]*a1v.w;
    ps2 += acc[4*q+0]*a2v.x + acc[4*q+1]*a2v.y + acc[4*q+2]*a2v.z + acc[4*q+3]*a2v.w;
  }
  red1[r * 8 + (t >> 5)] = ps1;
  red2[r * 8 + (t >> 5)] = ps2;

#pragma unroll
  for (int j = 0; j < 16; ++j) {
    unsigned b = __float_as_uint(acc[j]);
    hT[(unsigned)(c0 + j) * NN + (unsigned)(ib + r)] = (ushort_t)((b + 0x8000u) >> 16);
  }
  __syncthreads();
  if (t < 32) {
    float s1 = 0.f, s2 = 0.f;
#pragma unroll
    for (int g2 = 0; g2 < 8; ++g2) { s1 += red1[t * 8 + g2]; s2 += red2[t * 8 + g2]; }
    s1g[ib + t] = s1;
    Ug[ib + t] = expf(s2);
    Vg[ib + t] = expf(0.01f * s2);
  }
}

// ---------------- Kernel 3: fused masked-softmax @ h, barrier-free main loop
// Grid: 512 blocks (16 output rows each). Block: 512 threads = 8 waves.
// Wave w: rows rb..rb+15, cols 0..127, j-slice [w*1024, w*1024+1024).
// A-fragment (attention weights) computed per-lane in registers; B-fragment
// loaded directly from L2-resident hT. No LDS, no barriers until the final
// partial-sum reduction (softmax shift m_i is data-independent -> partials add).
__global__ __launch_bounds__(512, 2)
void k3_attn(const int* __restrict__ adj, const float* __restrict__ s1g,
             const float* __restrict__ Ug, const float* __restrict__ Vg,
             const ushort_t* __restrict__ hT, float* __restrict__ out)
{
  __shared__ float accL[8][16][128];   // 64 KB: per-wave partial C tiles
  __shared__ float zL[8][16];

  const int t = threadIdx.x;
  const int lane = t & 63, w = t >> 6;
  const int rowl = lane & 15, kq = lane >> 4;
  const int rb = blockIdx.x * 16;
  const int jb = w * 1024 + kq * 8;

  // per-row softmax factorization: w[i][j] = adj ? (U_j>E_i ? P_i*U_j : Q_i*V_j) : 0
  // with shift m_i = leaky(s1_i) + 24 (upper bound of row max; shift-invariant)
  const float s1v = s1g[rb + rowl];
  const float lv = s1v > 0.f ? s1v : 0.01f * s1v;
  const float P = expf(s1v - lv - 24.f);
  const float Q = expf(0.01f * s1v - lv - 24.f);
  const float E = expf(-s1v);

  f32x4 acc[8];
#pragma unroll
  for (int n = 0; n < 8; ++n) { acc[n][0] = 0.f; acc[n][1] = 0.f; acc[n][2] = 0.f; acc[n][3] = 0.f; }
  float z = 0.f;

  const i32x4* adjv = (const i32x4*)(adj + (size_t)(rb + rowl) * NN + jb);
  const float4* Uv = (const float4*)(Ug + jb);
  const float4* Vv = (const float4*)(Vg + jb);
  const ushort_t* hp[8];
#pragma unroll
  for (int n = 0; n < 8; ++n) hp[n] = hT + (size_t)(n * 16 + rowl) * NN + jb;

#pragma unroll 2
  for (int ks = 0; ks < 32; ++ks) {
    // adj streamed once -> non-temporal to spare L2 for hT
    i32x4 A0 = __builtin_nontemporal_load(adjv + ks * 8);
    i32x4 A1 = __builtin_nontemporal_load(adjv + ks * 8 + 1);
    float4 u0 = Uv[ks * 8], u1 = Uv[ks * 8 + 1];
    float4 v0 = Vv[ks * 8], v1 = Vv[ks * 8 + 1];

    float w0 = u0.x > E ? P * u0.x : Q * v0.x;  w0 = A0[0] > 0 ? w0 : 0.f;
    float w1 = u0.y > E ? P * u0.y : Q * v0.y;  w1 = A0[1] > 0 ? w1 : 0.f;
    float w2 = u0.z > E ? P * u0.z : Q * v0.z;  w2 = A0[2] > 0 ? w2 : 0.f;
    float w3 = u0.w > E ? P * u0.w : Q * v0.w;  w3 = A0[3] > 0 ? w3 : 0.f;
    float w4 = u1.x > E ? P * u1.x : Q * v1.x;  w4 = A1[0] > 0 ? w4 : 0.f;
    float w5 = u1.y > E ? P * u1.y : Q * v1.y;  w5 = A1[1] > 0 ? w5 : 0.f;
    float w6 = u1.z > E ? P * u1.z : Q * v1.z;  w6 = A1[2] > 0 ? w6 : 0.f;
    float w7 = u1.w > E ? P * u1.w : Q * v1.w;  w7 = A1[3] > 0 ? w7 : 0.f;
    z += ((w0 + w1) + (w2 + w3)) + ((w4 + w5) + (w6 + w7));

    unsigned p0 = ((__float_as_uint(w0) + 0x8000u) >> 16) | ((__float_as_uint(w1) + 0x8000u) & 0xFFFF0000u);
    unsigned p1 = ((__float_as_uint(w2) + 0x8000u) >> 16) | ((__float_as_uint(w3) + 0x8000u) & 0xFFFF0000u);
    unsigned p2 = ((__float_as_uint(w4) + 0x8000u) >> 16) | ((__float_as_uint(w5) + 0x8000u) & 0xFFFF0000u);
    unsigned p3 = ((__float_as_uint(w6) + 0x8000u) >> 16) | ((__float_as_uint(w7) + 0x8000u) & 0xFFFF0000u);
    union { unsigned u[4]; s16x8 v; } afu;
    afu.u[0] = p0; afu.u[1] = p1; afu.u[2] = p2; afu.u[3] = p3;
    s16x8 af = afu.v;

#pragma unroll
    for (int n = 0; n < 8; ++n) {
      s16x8 bf = *(const s16x8*)(hp[n] + ks * 32);
      acc[n] = __builtin_amdgcn_mfma_f32_16x16x32_bf16(af, bf, acc[n], 0, 0, 0);
    }
  }

  // z currently: partial over (kq's 8-k comb within each kstep) x this wave's j-slice
  z += __shfl_xor(z, 16);
  z += __shfl_xor(z, 32);   // now full row-sum for this wave's j-slice

  // stage partials; C/D layout: col = lane&15, row = (lane>>4)*4 + reg
#pragma unroll
  for (int n = 0; n < 8; ++n)
#pragma unroll
    for (int r2 = 0; r2 < 4; ++r2)
      accL[w][kq * 4 + r2][n * 16 + rowl] = acc[n][r2];
  if (lane < 16) zL[w][lane] = z;
  __syncthreads();

  // combine 8 j-slices, normalize, store
  {
    const int idx = t * 4;             // 0..2044, covers 16x128
    const int row = idx >> 7, col = idx & 127;
    f32x4 s; s[0] = 0.f; s[1] = 0.f; s[2] = 0.f; s[3] = 0.f;
    float zs = 0.f;
#pragma unroll
    for (int w2 = 0; w2 < 8; ++w2) {
      s += *(const f32x4*)&accL[w2][row][col];
      zs += zL[w2][row];
    }
    const float rz = 1.f / zs;
    float4 o;
    o.x = s[0] * rz; o.y = s[1] * rz; o.z = s[2] * rz; o.w = s[3] * rz;
    *(float4*)(out + (size_t)(rb + row) * FF + col) = o;
  }
}

extern "C" void kernel_launch(void* const* d_in, const int* in_sizes, int n_in,
                              void* d_out, int out_size, void* d_ws, size_t ws_size,
                              hipStream_t stream)
{
  const float* inp = (const float*)d_in[0];
  const int* adj   = (const int*)d_in[1];
  const float* W   = (const float*)d_in[2];
  const float* a   = (const float*)d_in[3];
  float* out = (float*)d_out;

  char* ws = (char*)d_ws;
  ushort_t* hT = (ushort_t*)ws;                                   // 2 MB
  float* s1g = (float*)(ws + (size_t)(2u << 20));                 // 32 KB
  float* Ug  = (float*)(ws + (size_t)(2u << 20) + (32u << 10));   // 32 KB
  float* Vg  = (float*)(ws + (size_t)(2u << 20) + (64u << 10));   // 32 KB

  hipLaunchKernelGGL(k1_hw, dim3(256), dim3(256), 0, stream, inp, W, a, hT, s1g, Ug, Vg);
  hipLaunchKernelGGL(k3_attn, dim3(512), dim3(512), 0, stream, adj, s1g, Ug, Vg, hT, out);
}